// Round 6
// baseline (211.420 us; speedup 1.0000x reference)
//
#include <hip/hip_runtime.h>
#include <math.h>

#define COS_EPS 1e-8f

typedef float vfloat4 __attribute__((ext_vector_type(4)));

__device__ __forceinline__ float dot4(vfloat4 a, vfloat4 b) {
    return fmaf(a.x, b.x, fmaf(a.y, b.y, fmaf(a.z, b.z, a.w * b.w)));
}

// R5 structure (single pass, wave-per-sample, 2-deep software pipeline,
// atomicAdd tail, separate finalize, NO device-scope fences).
// R6 change: grid 1024 -> 2048 (32 waves/CU, full occupancy) to double
// the loads in flight per SIMD and halve exposed memory latency.
__global__ __launch_bounds__(256) void assignment_loss_kernel(
    const float* __restrict__ emb,      // [B, D]
    const int*   __restrict__ labels,   // [B]
    const float* __restrict__ protos,   // [C, D]
    float*       __restrict__ acc,      // [1] pre-zeroed
    int B, int D)
{
    const int lane = threadIdx.x & 63;
    const int wib  = threadIdx.x >> 6;
    const int wpb  = blockDim.x >> 6;
    const int gw   = blockIdx.x * wpb + wib;
    const int nw   = gridDim.x * wpb;

    float local = 0.0f;

    if (D == 512 && (B % nw) == 0 && (B / nw) >= 3) {
        const int iters = B / nw;          // 8 for B=65536, nw=8192
        int s = gw;

        // ---- prologue: rows for sample s, label for sample s+nw ----
        int lbl0    = labels[s];           // wave-uniform -> s_load
        int lbl_nxt = labels[s + nw];
        const vfloat4* e0 = (const vfloat4*)(emb    + (size_t)s    * 512);
        const vfloat4* p0 = (const vfloat4*)(protos + (size_t)lbl0 * 512);
        vfloat4 ea = e0[lane], eb = e0[64 + lane];
        vfloat4 pa = p0[lane], pb = p0[64 + lane];

        // ---- steady state: issue next loads BEFORE reducing current ----
        for (int i = 0; i < iters - 2; ++i) {
            const int sn = s + nw;
            const int lbl_n2 = labels[s + 2 * nw];    // depth-2 label prefetch

            const vfloat4* e1 = (const vfloat4*)(emb    + (size_t)sn      * 512);
            const vfloat4* p1 = (const vfloat4*)(protos + (size_t)lbl_nxt * 512);
            vfloat4 ean = e1[lane], ebn = e1[64 + lane];
            vfloat4 pan = p1[lane], pbn = p1[64 + lane];

            float dot = dot4(ea, pa) + dot4(eb, pb);
            float esq = dot4(ea, ea) + dot4(eb, eb);
            float psq = dot4(pa, pa) + dot4(pb, pb);
            #pragma unroll
            for (int off = 32; off > 0; off >>= 1) {
                dot += __shfl_xor(dot, off, 64);
                esq += __shfl_xor(esq, off, 64);
                psq += __shfl_xor(psq, off, 64);
            }
            if (lane == 0) {
                float en = fmaxf(sqrtf(esq), COS_EPS);
                float pn = fmaxf(sqrtf(psq), COS_EPS);
                local += dot / (en * pn);
            }

            s = sn; lbl_nxt = lbl_n2;
            ea = ean; eb = ebn; pa = pan; pb = pbn;
        }

        // ---- epilogue iteration: load final rows, reduce current ----
        {
            const int sn = s + nw;
            const vfloat4* e1 = (const vfloat4*)(emb    + (size_t)sn      * 512);
            const vfloat4* p1 = (const vfloat4*)(protos + (size_t)lbl_nxt * 512);
            vfloat4 ean = e1[lane], ebn = e1[64 + lane];
            vfloat4 pan = p1[lane], pbn = p1[64 + lane];

            float dot = dot4(ea, pa) + dot4(eb, pb);
            float esq = dot4(ea, ea) + dot4(eb, eb);
            float psq = dot4(pa, pa) + dot4(pb, pb);
            #pragma unroll
            for (int off = 32; off > 0; off >>= 1) {
                dot += __shfl_xor(dot, off, 64);
                esq += __shfl_xor(esq, off, 64);
                psq += __shfl_xor(psq, off, 64);
            }
            if (lane == 0) {
                float en = fmaxf(sqrtf(esq), COS_EPS);
                float pn = fmaxf(sqrtf(psq), COS_EPS);
                local += dot / (en * pn);
            }
            ea = ean; eb = ebn; pa = pan; pb = pbn;
        }

        // ---- final sample ----
        {
            float dot = dot4(ea, pa) + dot4(eb, pb);
            float esq = dot4(ea, ea) + dot4(eb, eb);
            float psq = dot4(pa, pa) + dot4(pb, pb);
            #pragma unroll
            for (int off = 32; off > 0; off >>= 1) {
                dot += __shfl_xor(dot, off, 64);
                esq += __shfl_xor(esq, off, 64);
                psq += __shfl_xor(psq, off, 64);
            }
            if (lane == 0) {
                float en = fmaxf(sqrtf(esq), COS_EPS);
                float pn = fmaxf(sqrtf(psq), COS_EPS);
                local += dot / (en * pn);
            }
        }
    } else {
        // generic fallback (any D multiple of 256, any B)
        const int nchunks = D >> 8;
        for (int s = gw; s < B; s += nw) {
            const int lbl = labels[s];
            const vfloat4* e = (const vfloat4*)(emb    + (size_t)s   * (size_t)D);
            const vfloat4* p = (const vfloat4*)(protos + (size_t)lbl * (size_t)D);
            float dot = 0.f, esq = 0.f, psq = 0.f;
            for (int c = 0; c < nchunks; ++c) {
                vfloat4 ev = e[c * 64 + lane];
                vfloat4 pv = p[c * 64 + lane];
                dot += dot4(ev, pv);
                esq += dot4(ev, ev);
                psq += dot4(pv, pv);
            }
            #pragma unroll
            for (int off = 32; off > 0; off >>= 1) {
                dot += __shfl_xor(dot, off, 64);
                esq += __shfl_xor(esq, off, 64);
                psq += __shfl_xor(psq, off, 64);
            }
            if (lane == 0) {
                float en = fmaxf(sqrtf(esq), COS_EPS);
                float pn = fmaxf(sqrtf(psq), COS_EPS);
                local += dot / (en * pn);
            }
        }
    }

    // block reduction: one partial per wave -> LDS -> one atomic per block
    __shared__ float smem[8];
    if (lane == 0) smem[wib] = local;
    __syncthreads();
    if (threadIdx.x == 0) {
        float bs = 0.0f;
        for (int w = 0; w < wpb; ++w) bs += smem[w];
        atomicAdd(acc, bs);
    }
}

__global__ void assignment_loss_finalize(const float* __restrict__ acc,
                                         float* __restrict__ out,
                                         float invB)
{
    out[0] = 1.0f - acc[0] * invB;
}

extern "C" void kernel_launch(void* const* d_in, const int* in_sizes, int n_in,
                              void* d_out, int out_size, void* d_ws, size_t ws_size,
                              hipStream_t stream) {
    const float* emb    = (const float*)d_in[0];   // [B, D] float32
    const int*   labels = (const int*)  d_in[1];   // [B]
    const float* protos = (const float*)d_in[2];   // [C, D] float32
    float*       out    = (float*)d_out;           // scalar float32
    float*       acc    = (float*)d_ws;

    const int B = in_sizes[1];
    const int D = in_sizes[0] / B;                 // 512

    hipMemsetAsync(acc, 0, sizeof(float), stream); // d_ws poisoned 0xAA each call

    const int block = 256;                         // 4 waves/block
    const int grid  = 2048;                        // 32 waves/CU: full occupancy
    assignment_loss_kernel<<<grid, block, 0, stream>>>(emb, labels, protos, acc, B, D);
    assignment_loss_finalize<<<1, 1, 0, stream>>>(acc, out, 1.0f / (float)B);
}

// Round 7
// 209.219 us; speedup vs baseline: 1.0105x; 1.0105x over previous
//
#include <hip/hip_runtime.h>
#include <math.h>

#define COS_EPS 1e-8f

typedef float vfloat4 __attribute__((ext_vector_type(4)));

__device__ __forceinline__ float dot4(vfloat4 a, vfloat4 b) {
    return fmaf(a.x, b.x, fmaf(a.y, b.y, fmaf(a.z, b.z, a.w * b.w)));
}

// R7: quarter-wave mapping. 16 lanes per sample, 4 samples per wave.
// Each lane reads 8 float4 chunks of its group's emb row + gathered proto
// row (16 independent loads issued before any reduce). One 4-step
// butterfly (masks 1/2/4/8, DPP-able) reduces all 4 samples at once:
// cross-lane ops per sample drop 6x vs wave-per-sample. Labels prefetched
// one iteration ahead. atomicAdd tail + separate finalize (no fences).
__global__ __launch_bounds__(256) void assignment_loss_kernel(
    const float* __restrict__ emb,      // [B, D]
    const int*   __restrict__ labels,   // [B]
    const float* __restrict__ protos,   // [C, D]
    float*       __restrict__ acc,      // [1] pre-zeroed
    int B, int D)
{
    const int lane = threadIdx.x & 63;
    const int grp  = lane >> 4;         // 0..3: which sample in the wave
    const int gl   = lane & 15;         // lane within group
    const int wib  = threadIdx.x >> 6;
    const int wpb  = blockDim.x >> 6;
    const int gw   = blockIdx.x * wpb + wib;
    const int nw   = gridDim.x * wpb;

    float local = 0.0f;

    if (D == 512 && (B % (4 * nw)) == 0) {
        const int iters = B / (4 * nw);     // 4 for B=65536, nw=4096
        int s   = gw * 4 + grp;             // this lane's sample
        int lbl = labels[s];                // 4 distinct dwords per wave

        for (int i = 0; i < iters; ++i) {
            const int s_next   = s + 4 * nw;
            const int lbl_next = (i + 1 < iters) ? labels[s_next] : 0;  // prefetch

            const vfloat4* e = (const vfloat4*)(emb    + (size_t)s   * 512);
            const vfloat4* p = (const vfloat4*)(protos + (size_t)lbl * 512);

            // 16 independent loads: 4 rows x 4KB in flight before any use
            vfloat4 ev[8], pv[8];
            #pragma unroll
            for (int c = 0; c < 8; ++c) ev[c] = e[c * 16 + gl];
            #pragma unroll
            for (int c = 0; c < 8; ++c) pv[c] = p[c * 16 + gl];

            float dot = 0.f, esq = 0.f, psq = 0.f;
            #pragma unroll
            for (int c = 0; c < 8; ++c) {
                dot += dot4(ev[c], pv[c]);
                esq += dot4(ev[c], ev[c]);
                psq += dot4(pv[c], pv[c]);
            }

            // 4-step butterfly within each 16-lane group (reduces 4 samples at once)
            #pragma unroll
            for (int off = 8; off > 0; off >>= 1) {
                dot += __shfl_xor(dot, off, 64);
                esq += __shfl_xor(esq, off, 64);
                psq += __shfl_xor(psq, off, 64);
            }

            if (gl == 0) {
                float en = fmaxf(sqrtf(esq), COS_EPS);  // torch eps semantics
                float pn = fmaxf(sqrtf(psq), COS_EPS);
                local += dot / (en * pn);
            }

            s = s_next; lbl = lbl_next;
        }
    } else {
        // generic fallback: wave-per-sample, any D multiple of 256
        const int nchunks = D >> 8;
        for (int smp = gw; smp < B; smp += nw) {
            const int l = labels[smp];
            const vfloat4* e = (const vfloat4*)(emb    + (size_t)smp * (size_t)D);
            const vfloat4* p = (const vfloat4*)(protos + (size_t)l   * (size_t)D);
            float dot = 0.f, esq = 0.f, psq = 0.f;
            for (int c = 0; c < nchunks; ++c) {
                vfloat4 ev = e[c * 64 + lane];
                vfloat4 pv = p[c * 64 + lane];
                dot += dot4(ev, pv);
                esq += dot4(ev, ev);
                psq += dot4(pv, pv);
            }
            #pragma unroll
            for (int off = 32; off > 0; off >>= 1) {
                dot += __shfl_xor(dot, off, 64);
                esq += __shfl_xor(esq, off, 64);
                psq += __shfl_xor(psq, off, 64);
            }
            if (lane == 0) {
                float en = fmaxf(sqrtf(esq), COS_EPS);
                float pn = fmaxf(sqrtf(psq), COS_EPS);
                local += dot / (en * pn);
            }
        }
    }

    // local is nonzero on group-leader lanes; full-wave butterfly once,
    // then LDS across waves, one atomic per block
    #pragma unroll
    for (int off = 32; off > 0; off >>= 1) local += __shfl_xor(local, off, 64);

    __shared__ float smem[8];
    if (lane == 0) smem[wib] = local;
    __syncthreads();
    if (threadIdx.x == 0) {
        float bs = 0.0f;
        for (int w = 0; w < wpb; ++w) bs += smem[w];
        atomicAdd(acc, bs);
    }
}

__global__ void assignment_loss_finalize(const float* __restrict__ acc,
                                         float* __restrict__ out,
                                         float invB)
{
    out[0] = 1.0f - acc[0] * invB;
}

extern "C" void kernel_launch(void* const* d_in, const int* in_sizes, int n_in,
                              void* d_out, int out_size, void* d_ws, size_t ws_size,
                              hipStream_t stream) {
    const float* emb    = (const float*)d_in[0];   // [B, D] float32
    const int*   labels = (const int*)  d_in[1];   // [B]
    const float* protos = (const float*)d_in[2];   // [C, D] float32
    float*       out    = (float*)d_out;           // scalar float32
    float*       acc    = (float*)d_ws;

    const int B = in_sizes[1];
    const int D = in_sizes[0] / B;                 // 512

    hipMemsetAsync(acc, 0, sizeof(float), stream); // d_ws poisoned 0xAA each call

    const int block = 256;                         // 4 waves/block
    const int grid  = 1024;                        // 4096 waves; occupancy proven non-binding (R6)
    assignment_loss_kernel<<<grid, block, 0, stream>>>(emb, labels, protos, acc, B, D);
    assignment_loss_finalize<<<1, 1, 0, stream>>>(acc, out, 1.0f / (float)B);
}